// Round 6
// baseline (691.711 us; speedup 1.0000x reference)
//
#include <hip/hip_runtime.h>
#include <math.h>

// BeliveMapsNMS: 7x7 same-padded max-pool NMS on [32,4,512,512] f32.
// Outputs (concat flat): mask(0/1 f32), scores_abs, scores_rel.
// R6: R5 structure (split-row lanes, shuffle van Herk, register rolling,
// no LDS/no barriers) with PLAIN stores. R4/R5 measured: nontemporal stores
// bypass L2 write-combining -> sector RMW at HBM -> 1.7x WRITE_SIZE + extra
// FETCH (714MB/267MB vs 403/184 mandatory). Plain stores merge in L2.

#define H 512
#define W 512
#define PLANE_ELEMS (H * W)   // 262144
#define S 16                  // rows per wave
#define NEG_INF (-INFINITY)

struct Row8 { float4 lo, hi; };  // lo: cols 4L..4L+3, hi: cols 256+4L..256+4L+3

__device__ __forceinline__ float4 vmax4(float4 a, float4 b) {
    return make_float4(fmaxf(a.x, b.x), fmaxf(a.y, b.y), fmaxf(a.z, b.z), fmaxf(a.w, b.w));
}
__device__ __forceinline__ Row8 vmax8(Row8 a, Row8 b) {
    Row8 r; r.lo = vmax4(a.lo, b.lo); r.hi = vmax4(a.hi, b.hi); return r;
}

// Wave-uniform gy; contiguous 1KB/wave per segment load.
__device__ __forceinline__ Row8 loadRow(const float* __restrict__ pin, int gy, int c4) {
    Row8 r;
    if (gy >= 0 && gy < H) {
        const float* row = pin + (size_t)gy * W;
        r.lo = *(const float4*)(row + c4);
        r.hi = *(const float4*)(row + 256 + c4);
    } else {
        r.lo = r.hi = make_float4(NEG_INF, NEG_INF, NEG_INF, NEG_INF);
    }
    return r;
}

// m[j] = max(a[j..j+6]) for j=0..3 over a 10-elem window (van Herk split).
__device__ __forceinline__ float4 win7_4(const float a[10]) {
    float s6 = a[6];
    float s5 = fmaxf(a[5], s6), s4 = fmaxf(a[4], s5), s3 = fmaxf(a[3], s4);
    float s2 = fmaxf(a[2], s3), s1 = fmaxf(a[1], s2), s0 = fmaxf(a[0], s1);
    float p7 = a[7], p8 = fmaxf(p7, a[8]), p9 = fmaxf(p8, a[9]);
    return make_float4(s0, fmaxf(s1, p7), fmaxf(s2, p8), fmaxf(s3, p9));
}

// Horizontal 7-max in split layout. 12 neighbor shuffles + 6 seam broadcasts.
__device__ __forceinline__ Row8 hmax7(Row8 v, int lane) {
    float ll0 = __shfl_up(v.lo.y, 1, 64), ll1 = __shfl_up(v.lo.z, 1, 64), ll2 = __shfl_up(v.lo.w, 1, 64);
    float lr0 = __shfl_down(v.lo.x, 1, 64), lr1 = __shfl_down(v.lo.y, 1, 64), lr2 = __shfl_down(v.lo.z, 1, 64);
    float hl0 = __shfl_up(v.hi.y, 1, 64), hl1 = __shfl_up(v.hi.z, 1, 64), hl2 = __shfl_up(v.hi.w, 1, 64);
    float hr0 = __shfl_down(v.hi.x, 1, 64), hr1 = __shfl_down(v.hi.y, 1, 64), hr2 = __shfl_down(v.hi.z, 1, 64);
    // seam: lane63.lo (cols 253..255) <-> lane0.hi (cols 256..258)
    float sly = __shfl(v.lo.y, 63, 64), slz = __shfl(v.lo.z, 63, 64), slw = __shfl(v.lo.w, 63, 64);
    float shx = __shfl(v.hi.x, 0, 64), shy = __shfl(v.hi.y, 0, 64), shz = __shfl(v.hi.z, 0, 64);
    if (lane == 0) { ll0 = NEG_INF; ll1 = NEG_INF; ll2 = NEG_INF; hl0 = sly; hl1 = slz; hl2 = slw; }
    if (lane == 63) { lr0 = shx; lr1 = shy; lr2 = shz; hr0 = NEG_INF; hr1 = NEG_INF; hr2 = NEG_INF; }
    float alo[10] = {ll0, ll1, ll2, v.lo.x, v.lo.y, v.lo.z, v.lo.w, lr0, lr1, lr2};
    float ahi[10] = {hl0, hl1, hl2, v.hi.x, v.hi.y, v.hi.z, v.hi.w, hr0, hr1, hr2};
    Row8 out;
    out.lo = win7_4(alo);
    out.hi = win7_4(ahi);
    return out;
}

__device__ __forceinline__ void emit4(float* p, bool s0, bool s1, bool s2, bool s3,
                                      float4 ctr, float inv_vmax, float* pa, float* pr) {
    const float a0 = s0 ? ctr.x : 0.0f, a1 = s1 ? ctr.y : 0.0f;
    const float a2 = s2 ? ctr.z : 0.0f, a3 = s3 ? ctr.w : 0.0f;
    *(float4*)p = make_float4(s0 ? 1.0f : 0.0f, s1 ? 1.0f : 0.0f,
                              s2 ? 1.0f : 0.0f, s3 ? 1.0f : 0.0f);
    *(float4*)pa = make_float4(a0, a1, a2, a3);
    *(float4*)pr = make_float4(a0 * inv_vmax, a1 * inv_vmax, a2 * inv_vmax, a3 * inv_vmax);
}

__device__ __forceinline__ void emitRow(float* __restrict__ om, float* __restrict__ oa,
                                        float* __restrict__ orl, size_t off,
                                        Row8 m, Row8 ctr, float rel_thr, float inv_vmax) {
    const bool p0 = (m.lo.x == ctr.lo.x) & (ctr.lo.x > 0.2f) & (ctr.lo.x > rel_thr);
    const bool p1 = (m.lo.y == ctr.lo.y) & (ctr.lo.y > 0.2f) & (ctr.lo.y > rel_thr);
    const bool p2 = (m.lo.z == ctr.lo.z) & (ctr.lo.z > 0.2f) & (ctr.lo.z > rel_thr);
    const bool p3 = (m.lo.w == ctr.lo.w) & (ctr.lo.w > 0.2f) & (ctr.lo.w > rel_thr);
    const bool q0 = (m.hi.x == ctr.hi.x) & (ctr.hi.x > 0.2f) & (ctr.hi.x > rel_thr);
    const bool q1 = (m.hi.y == ctr.hi.y) & (ctr.hi.y > 0.2f) & (ctr.hi.y > rel_thr);
    const bool q2 = (m.hi.z == ctr.hi.z) & (ctr.hi.z > 0.2f) & (ctr.hi.z > rel_thr);
    const bool q3 = (m.hi.w == ctr.hi.w) & (ctr.hi.w > 0.2f) & (ctr.hi.w > rel_thr);
    emit4(om + off, p0, p1, p2, p3, ctr.lo, inv_vmax, oa + off, orl + off);
    emit4(om + off + 256, q0, q1, q2, q3, ctr.hi, inv_vmax, oa + off + 256, orl + off + 256);
}

// ---------------- Pass 1: per-plane max ----------------
__global__ __launch_bounds__(256) void vmax_kernel(const float* __restrict__ in,
                                                   unsigned int* __restrict__ vmax_bits) {
    const int q = blockIdx.x;      // 4 quarters
    const int plane = blockIdx.y;  // 128 planes
    const float4* p = (const float4*)(in + (size_t)plane * PLANE_ELEMS + q * (PLANE_ELEMS / 4));
    float m = 0.0f;  // inputs in [0,1): non-negative
    const int nvec = PLANE_ELEMS / 4 / 4;
    for (int i = threadIdx.x; i < nvec; i += 256) {
        float4 v = p[i];
        m = fmaxf(m, fmaxf(fmaxf(v.x, v.y), fmaxf(v.z, v.w)));
    }
    #pragma unroll
    for (int o = 32; o > 0; o >>= 1) m = fmaxf(m, __shfl_down(m, o, 64));
    __shared__ float s[4];
    if ((threadIdx.x & 63) == 0) s[threadIdx.x >> 6] = m;
    __syncthreads();
    if (threadIdx.x == 0) {
        m = fmaxf(fmaxf(s[0], s[1]), fmaxf(s[2], s[3]));
        atomicMax(&vmax_bits[plane], __float_as_uint(m));  // non-neg: uint order == float order
    }
}

// ---------------- Pass 2: streaming NMS ----------------
__global__ __launch_bounds__(256, 4) void nms_kernel(const float* __restrict__ in,
                                                     const unsigned int* __restrict__ vmax_bits,
                                                     float* __restrict__ out, int N) {
    const int plane = blockIdx.y;
    const int wid = threadIdx.x >> 6;
    const int lane = threadIdx.x & 63;
    const int c4 = lane << 2;
    const int r0 = (blockIdx.x * 4 + wid) * S;   // stripe start row for this wave
    const float* pin = in + (size_t)plane * PLANE_ELEMS;

    const float vmaxv = __uint_as_float(vmax_bits[plane]);
    const float rel_thr = 0.05f * vmaxv;
    const float inv_vmax = 1.0f / vmaxv;

    float* __restrict__ omask = out;
    float* __restrict__ oabs = out + (size_t)N;
    float* __restrict__ orel = out + 2 * (size_t)N;
    const size_t planeBase = (size_t)plane * PLANE_ELEMS;

    // Prologue: hist = rowmax of rows r0-3..r0+2; raw lag = rows r0..r0+2.
    Row8 hist[6], raw[3], fresh[4];
    #pragma unroll
    for (int j = 0; j < 6; ++j) {
        Row8 rr = loadRow(pin, r0 - 3 + j, c4);
        hist[j] = hmax7(rr, lane);
        if (j >= 3) raw[j - 3] = rr;
    }
    #pragma unroll
    for (int j = 0; j < 4; ++j) fresh[j] = loadRow(pin, r0 + 3 + j, c4);

    #pragma unroll
    for (int k = 0; k < S / 4; ++k) {
        const int R = r0 + 4 * k;
        // Prefetch next batch's raw rows before computing this batch.
        Row8 nxt[4];
        if (k < S / 4 - 1) {
            #pragma unroll
            for (int j = 0; j < 4; ++j) nxt[j] = loadRow(pin, R + 7 + j, c4);
        }
        // Horizontal 7-max of fresh rows R+3..R+6.
        Row8 hm[4];
        #pragma unroll
        for (int j = 0; j < 4; ++j) hm[j] = hmax7(fresh[j], lane);
        // Vertical van Herk: out[R+i] = max(rowmax[R+i-3 .. R+i+3]).
        Row8 sfx = vmax8(hist[4], hist[5]);
        Row8 A3 = vmax8(hist[3], sfx);
        Row8 A2 = vmax8(hist[2], A3);
        Row8 A1 = vmax8(hist[1], A2);
        Row8 A0 = vmax8(hist[0], A1);
        Row8 B0 = hm[0];
        Row8 B1 = vmax8(B0, hm[1]);
        Row8 B2 = vmax8(B1, hm[2]);
        Row8 B3 = vmax8(B2, hm[3]);
        const size_t off = planeBase + (size_t)R * W + c4;
        emitRow(omask, oabs, orel, off,         vmax8(A0, B0), raw[0],   rel_thr, inv_vmax);
        emitRow(omask, oabs, orel, off + W,     vmax8(A1, B1), raw[1],   rel_thr, inv_vmax);
        emitRow(omask, oabs, orel, off + 2 * W, vmax8(A2, B2), raw[2],   rel_thr, inv_vmax);
        emitRow(omask, oabs, orel, off + 3 * W, vmax8(A3, B3), fresh[0], rel_thr, inv_vmax);
        // Rotate state (register renaming under full unroll).
        hist[0] = hist[4]; hist[1] = hist[5];
        hist[2] = hm[0]; hist[3] = hm[1]; hist[4] = hm[2]; hist[5] = hm[3];
        raw[0] = fresh[1]; raw[1] = fresh[2]; raw[2] = fresh[3];
        fresh[0] = nxt[0]; fresh[1] = nxt[1]; fresh[2] = nxt[2]; fresh[3] = nxt[3];
    }
}

extern "C" void kernel_launch(void* const* d_in, const int* in_sizes, int n_in,
                              void* d_out, int out_size, void* d_ws, size_t ws_size,
                              hipStream_t stream) {
    const float* in = (const float*)d_in[0];
    float* out = (float*)d_out;
    const int N = in_sizes[0];           // 33554432
    const int planes = N / PLANE_ELEMS;  // 128

    unsigned int* vmax_bits = (unsigned int*)d_ws;
    (void)hipMemsetAsync(vmax_bits, 0, planes * sizeof(unsigned int), stream);

    vmax_kernel<<<dim3(4, planes), 256, 0, stream>>>(in, vmax_bits);
    // 4 waves/block, each wave a 16-row stripe: block covers 64 rows.
    nms_kernel<<<dim3(H / (4 * S), planes), 256, 0, stream>>>(in, vmax_bits, out, N);
}

// Round 7
// 650.478 us; speedup vs baseline: 1.0634x; 1.0634x over previous
//
#include <hip/hip_runtime.h>
#include <math.h>

// BeliveMapsNMS: 7x7 same-padded max-pool NMS on [32,4,512,512] f32.
// Outputs (concat flat): mask(0/1 f32), scores_abs, scores_rel — all zero
// except at peaks (~2% density on this input).
// R7: dense-write amplification (1.8x, R4-R6 measured, layout-independent)
// is sidestepped: memset d_out to 0 (single-stream fill = proven 1:1 at
// 6.3 TB/s), then a read-only streaming NMS kernel scatters only the peaks.

#define H 512
#define W 512
#define PLANE_ELEMS (H * W)   // 262144
#define S 16                  // rows per wave
#define NEG_INF (-INFINITY)

struct Row8 { float4 lo, hi; };  // 8 CONSECUTIVE cols per lane: [8L..8L+7]

__device__ __forceinline__ float4 vmax4(float4 a, float4 b) {
    return make_float4(fmaxf(a.x, b.x), fmaxf(a.y, b.y), fmaxf(a.z, b.z), fmaxf(a.w, b.w));
}
__device__ __forceinline__ Row8 vmax8(Row8 a, Row8 b) {
    Row8 r; r.lo = vmax4(a.lo, b.lo); r.hi = vmax4(a.hi, b.hi); return r;
}

// Wave covers one full row: lane L loads cols 8L..8L+7 (2 x float4).
__device__ __forceinline__ Row8 loadRow(const float* __restrict__ pin, int gy, int lane) {
    Row8 r;
    if (gy >= 0 && gy < H) {
        const float4* row = (const float4*)(pin + (size_t)gy * W);
        r.lo = row[lane * 2];
        r.hi = row[lane * 2 + 1];
    } else {
        r.lo = r.hi = make_float4(NEG_INF, NEG_INF, NEG_INF, NEG_INF);
    }
    return r;
}

// Horizontal 7-max (van Herk) with shuffle halo — verified R3/R4.
__device__ __forceinline__ Row8 hmax7(Row8 v, int lane) {
    float l0 = __shfl_up(v.hi.y, 1, 64), l1 = __shfl_up(v.hi.z, 1, 64), l2 = __shfl_up(v.hi.w, 1, 64);
    float r0 = __shfl_down(v.lo.x, 1, 64), r1 = __shfl_down(v.lo.y, 1, 64), r2 = __shfl_down(v.lo.z, 1, 64);
    if (lane == 0) { l0 = NEG_INF; l1 = NEG_INF; l2 = NEG_INF; }
    if (lane == 63) { r0 = NEG_INF; r1 = NEG_INF; r2 = NEG_INF; }
    float a[14] = {l0, l1, l2, v.lo.x, v.lo.y, v.lo.z, v.lo.w,
                   v.hi.x, v.hi.y, v.hi.z, v.hi.w, r0, r1, r2};
    float A[7];
    A[6] = a[6];
    #pragma unroll
    for (int j = 5; j >= 0; --j) A[j] = fmaxf(a[j], A[j + 1]);
    float rm[8];
    rm[0] = A[0];
    float B = a[7];
    rm[1] = fmaxf(A[1], B);
    #pragma unroll
    for (int j = 2; j <= 6; ++j) { B = fmaxf(B, a[6 + j]); rm[j] = fmaxf(A[j], B); }
    B = fmaxf(B, a[13]);
    rm[7] = B;
    Row8 out;
    out.lo = make_float4(rm[0], rm[1], rm[2], rm[3]);
    out.hi = make_float4(rm[4], rm[5], rm[6], rm[7]);
    return out;
}

// Sparse emit: only peaks are written (outputs pre-zeroed by memset).
__device__ __forceinline__ void emitSparse(float* __restrict__ om, float* __restrict__ oa,
                                           float* __restrict__ orl, size_t off,
                                           Row8 m, Row8 ctr, float rel_thr, float inv_vmax) {
    const float mv[8] = {m.lo.x, m.lo.y, m.lo.z, m.lo.w, m.hi.x, m.hi.y, m.hi.z, m.hi.w};
    const float cv[8] = {ctr.lo.x, ctr.lo.y, ctr.lo.z, ctr.lo.w,
                         ctr.hi.x, ctr.hi.y, ctr.hi.z, ctr.hi.w};
    #pragma unroll
    for (int j = 0; j < 8; ++j) {
        const bool p = (mv[j] == cv[j]) & (cv[j] > 0.2f) & (cv[j] > rel_thr);
        if (p) {
            om[off + j] = 1.0f;
            oa[off + j] = cv[j];
            orl[off + j] = cv[j] * inv_vmax;
        }
    }
}

// ---------------- Pass 1: per-plane max ----------------
__global__ __launch_bounds__(256) void vmax_kernel(const float* __restrict__ in,
                                                   unsigned int* __restrict__ vmax_bits) {
    const int q = blockIdx.x;      // 4 quarters
    const int plane = blockIdx.y;  // 128 planes
    const float4* p = (const float4*)(in + (size_t)plane * PLANE_ELEMS + q * (PLANE_ELEMS / 4));
    float m = 0.0f;  // inputs in [0,1): non-negative
    const int nvec = PLANE_ELEMS / 4 / 4;
    for (int i = threadIdx.x; i < nvec; i += 256) {
        float4 v = p[i];
        m = fmaxf(m, fmaxf(fmaxf(v.x, v.y), fmaxf(v.z, v.w)));
    }
    #pragma unroll
    for (int o = 32; o > 0; o >>= 1) m = fmaxf(m, __shfl_down(m, o, 64));
    __shared__ float s[4];
    if ((threadIdx.x & 63) == 0) s[threadIdx.x >> 6] = m;
    __syncthreads();
    if (threadIdx.x == 0) {
        m = fmaxf(fmaxf(s[0], s[1]), fmaxf(s[2], s[3]));
        atomicMax(&vmax_bits[plane], __float_as_uint(m));  // non-neg: uint order == float order
    }
}

// ---------------- Pass 2: streaming sparse NMS ----------------
__global__ __launch_bounds__(256, 4) void nms_kernel(const float* __restrict__ in,
                                                     const unsigned int* __restrict__ vmax_bits,
                                                     float* __restrict__ out, int N) {
    const int plane = blockIdx.y;
    const int wid = threadIdx.x >> 6;
    const int lane = threadIdx.x & 63;
    const int c8 = lane << 3;
    const int r0 = (blockIdx.x * 4 + wid) * S;   // stripe start row for this wave
    const float* pin = in + (size_t)plane * PLANE_ELEMS;

    const float vmaxv = __uint_as_float(vmax_bits[plane]);
    const float rel_thr = 0.05f * vmaxv;
    const float inv_vmax = 1.0f / vmaxv;

    float* __restrict__ omask = out;
    float* __restrict__ oabs = out + (size_t)N;
    float* __restrict__ orel = out + 2 * (size_t)N;
    const size_t planeBase = (size_t)plane * PLANE_ELEMS;

    // Prologue: hist = rowmax of rows r0-3..r0+2; raw lag = rows r0..r0+2.
    Row8 hist[6], raw[3], fresh[4];
    #pragma unroll
    for (int j = 0; j < 6; ++j) {
        Row8 rr = loadRow(pin, r0 - 3 + j, lane);
        hist[j] = hmax7(rr, lane);
        if (j >= 3) raw[j - 3] = rr;
    }
    #pragma unroll
    for (int j = 0; j < 4; ++j) fresh[j] = loadRow(pin, r0 + 3 + j, lane);

    #pragma unroll
    for (int k = 0; k < S / 4; ++k) {
        const int R = r0 + 4 * k;
        // Prefetch next batch's raw rows before computing this batch.
        Row8 nxt[4];
        if (k < S / 4 - 1) {
            #pragma unroll
            for (int j = 0; j < 4; ++j) nxt[j] = loadRow(pin, R + 7 + j, lane);
        }
        // Horizontal 7-max of fresh rows R+3..R+6.
        Row8 hm[4];
        #pragma unroll
        for (int j = 0; j < 4; ++j) hm[j] = hmax7(fresh[j], lane);
        // Vertical van Herk: out[R+i] = max(rowmax[R+i-3 .. R+i+3]).
        Row8 sfx = vmax8(hist[4], hist[5]);
        Row8 A3 = vmax8(hist[3], sfx);
        Row8 A2 = vmax8(hist[2], A3);
        Row8 A1 = vmax8(hist[1], A2);
        Row8 A0 = vmax8(hist[0], A1);
        Row8 B0 = hm[0];
        Row8 B1 = vmax8(B0, hm[1]);
        Row8 B2 = vmax8(B1, hm[2]);
        Row8 B3 = vmax8(B2, hm[3]);
        const size_t off = planeBase + (size_t)R * W + c8;
        emitSparse(omask, oabs, orel, off,         vmax8(A0, B0), raw[0],   rel_thr, inv_vmax);
        emitSparse(omask, oabs, orel, off + W,     vmax8(A1, B1), raw[1],   rel_thr, inv_vmax);
        emitSparse(omask, oabs, orel, off + 2 * W, vmax8(A2, B2), raw[2],   rel_thr, inv_vmax);
        emitSparse(omask, oabs, orel, off + 3 * W, vmax8(A3, B3), fresh[0], rel_thr, inv_vmax);
        // Rotate state (register renaming under full unroll).
        hist[0] = hist[4]; hist[1] = hist[5];
        hist[2] = hm[0]; hist[3] = hm[1]; hist[4] = hm[2]; hist[5] = hm[3];
        raw[0] = fresh[1]; raw[1] = fresh[2]; raw[2] = fresh[3];
        fresh[0] = nxt[0]; fresh[1] = nxt[1]; fresh[2] = nxt[2]; fresh[3] = nxt[3];
    }
}

extern "C" void kernel_launch(void* const* d_in, const int* in_sizes, int n_in,
                              void* d_out, int out_size, void* d_ws, size_t ws_size,
                              hipStream_t stream) {
    const float* in = (const float*)d_in[0];
    float* out = (float*)d_out;
    const int N = in_sizes[0];           // 33554432
    const int planes = N / PLANE_ELEMS;  // 128

    unsigned int* vmax_bits = (unsigned int*)d_ws;

    // Zero all three outputs first (single-stream dense fill: 1:1 writes at
    // ~6.3 TB/s per harness fill counters). Then vmax warms L3 with the input,
    // then the sparse NMS reads L3-warm input and scatters only peaks.
    (void)hipMemsetAsync(out, 0, (size_t)out_size * sizeof(float), stream);
    (void)hipMemsetAsync(vmax_bits, 0, planes * sizeof(unsigned int), stream);

    vmax_kernel<<<dim3(4, planes), 256, 0, stream>>>(in, vmax_bits);
    nms_kernel<<<dim3(H / (4 * S), planes), 256, 0, stream>>>(in, vmax_bits, out, N);
}

// Round 8
// 633.022 us; speedup vs baseline: 1.0927x; 1.0276x over previous
//
#include <hip/hip_runtime.h>
#include <math.h>

// BeliveMapsNMS: 7x7 same-padded max-pool NMS on [32,4,512,512] f32.
// Outputs (concat flat): mask(0/1 f32), scores_abs, scores_rel.
// R8: R4-R6 measured 1.78x write amplification whenever ONE kernel writes
// all 3 output streams (2^27 B apart); harness's single-stream fill is 1:1
// at 6.3 TB/s. mask = (abs != 0), rel = abs * inv_vmax are elementwise maps
// of abs -> split into 3 kernels, each writing exactly ONE dense stream:
//   vmax -> abs (van Herk NMS) -> mask (map) & rel (map).

#define H 512
#define W 512
#define PLANE_ELEMS (H * W)   // 262144
#define S 16                  // rows per wave in abs_kernel
#define NEG_INF (-INFINITY)

struct Row8 { float4 lo, hi; };  // 8 consecutive cols per lane: [8L..8L+7]

__device__ __forceinline__ float4 vmax4(float4 a, float4 b) {
    return make_float4(fmaxf(a.x, b.x), fmaxf(a.y, b.y), fmaxf(a.z, b.z), fmaxf(a.w, b.w));
}
__device__ __forceinline__ Row8 vmax8(Row8 a, Row8 b) {
    Row8 r; r.lo = vmax4(a.lo, b.lo); r.hi = vmax4(a.hi, b.hi); return r;
}

// Wave covers one full row: lane L loads cols 8L..8L+7 (2 x float4, 2KB/wave).
__device__ __forceinline__ Row8 loadRow(const float* __restrict__ pin, int gy, int lane) {
    Row8 r;
    if (gy >= 0 && gy < H) {
        const float4* row = (const float4*)(pin + (size_t)gy * W);
        r.lo = row[lane * 2];
        r.hi = row[lane * 2 + 1];
    } else {
        r.lo = r.hi = make_float4(NEG_INF, NEG_INF, NEG_INF, NEG_INF);
    }
    return r;
}

// Horizontal 7-max (van Herk) with shuffle halo — verified R3/R4/R7.
__device__ __forceinline__ Row8 hmax7(Row8 v, int lane) {
    float l0 = __shfl_up(v.hi.y, 1, 64), l1 = __shfl_up(v.hi.z, 1, 64), l2 = __shfl_up(v.hi.w, 1, 64);
    float r0 = __shfl_down(v.lo.x, 1, 64), r1 = __shfl_down(v.lo.y, 1, 64), r2 = __shfl_down(v.lo.z, 1, 64);
    if (lane == 0) { l0 = NEG_INF; l1 = NEG_INF; l2 = NEG_INF; }
    if (lane == 63) { r0 = NEG_INF; r1 = NEG_INF; r2 = NEG_INF; }
    float a[14] = {l0, l1, l2, v.lo.x, v.lo.y, v.lo.z, v.lo.w,
                   v.hi.x, v.hi.y, v.hi.z, v.hi.w, r0, r1, r2};
    float A[7];
    A[6] = a[6];
    #pragma unroll
    for (int j = 5; j >= 0; --j) A[j] = fmaxf(a[j], A[j + 1]);
    float rm[8];
    rm[0] = A[0];
    float B = a[7];
    rm[1] = fmaxf(A[1], B);
    #pragma unroll
    for (int j = 2; j <= 6; ++j) { B = fmaxf(B, a[6 + j]); rm[j] = fmaxf(A[j], B); }
    B = fmaxf(B, a[13]);
    rm[7] = B;
    Row8 out;
    out.lo = make_float4(rm[0], rm[1], rm[2], rm[3]);
    out.hi = make_float4(rm[4], rm[5], rm[6], rm[7]);
    return out;
}

// Single-stream emit: abs only, 2 contiguous float4 per lane.
__device__ __forceinline__ void emitAbs(float* __restrict__ oa, size_t off,
                                        Row8 m, Row8 ctr, float rel_thr) {
    const bool p0 = (m.lo.x == ctr.lo.x) & (ctr.lo.x > 0.2f) & (ctr.lo.x > rel_thr);
    const bool p1 = (m.lo.y == ctr.lo.y) & (ctr.lo.y > 0.2f) & (ctr.lo.y > rel_thr);
    const bool p2 = (m.lo.z == ctr.lo.z) & (ctr.lo.z > 0.2f) & (ctr.lo.z > rel_thr);
    const bool p3 = (m.lo.w == ctr.lo.w) & (ctr.lo.w > 0.2f) & (ctr.lo.w > rel_thr);
    const bool q0 = (m.hi.x == ctr.hi.x) & (ctr.hi.x > 0.2f) & (ctr.hi.x > rel_thr);
    const bool q1 = (m.hi.y == ctr.hi.y) & (ctr.hi.y > 0.2f) & (ctr.hi.y > rel_thr);
    const bool q2 = (m.hi.z == ctr.hi.z) & (ctr.hi.z > 0.2f) & (ctr.hi.z > rel_thr);
    const bool q3 = (m.hi.w == ctr.hi.w) & (ctr.hi.w > 0.2f) & (ctr.hi.w > rel_thr);
    *(float4*)(oa + off) = make_float4(p0 ? ctr.lo.x : 0.0f, p1 ? ctr.lo.y : 0.0f,
                                       p2 ? ctr.lo.z : 0.0f, p3 ? ctr.lo.w : 0.0f);
    *(float4*)(oa + off + 4) = make_float4(q0 ? ctr.hi.x : 0.0f, q1 ? ctr.hi.y : 0.0f,
                                           q2 ? ctr.hi.z : 0.0f, q3 ? ctr.hi.w : 0.0f);
}

// ---------------- Pass 1: per-plane max ----------------
__global__ __launch_bounds__(256) void vmax_kernel(const float* __restrict__ in,
                                                   unsigned int* __restrict__ vmax_bits) {
    const int q = blockIdx.x;      // 4 quarters
    const int plane = blockIdx.y;  // 128 planes
    const float4* p = (const float4*)(in + (size_t)plane * PLANE_ELEMS + q * (PLANE_ELEMS / 4));
    float m = 0.0f;  // inputs in [0,1): non-negative
    const int nvec = PLANE_ELEMS / 4 / 4;
    for (int i = threadIdx.x; i < nvec; i += 256) {
        float4 v = p[i];
        m = fmaxf(m, fmaxf(fmaxf(v.x, v.y), fmaxf(v.z, v.w)));
    }
    #pragma unroll
    for (int o = 32; o > 0; o >>= 1) m = fmaxf(m, __shfl_down(m, o, 64));
    __shared__ float s[4];
    if ((threadIdx.x & 63) == 0) s[threadIdx.x >> 6] = m;
    __syncthreads();
    if (threadIdx.x == 0) {
        m = fmaxf(fmaxf(s[0], s[1]), fmaxf(s[2], s[3]));
        atomicMax(&vmax_bits[plane], __float_as_uint(m));  // non-neg: uint order == float order
    }
}

// ---------------- Pass 2: streaming NMS -> abs only ----------------
__global__ __launch_bounds__(256, 4) void abs_kernel(const float* __restrict__ in,
                                                     const unsigned int* __restrict__ vmax_bits,
                                                     float* __restrict__ oabs) {
    const int plane = blockIdx.y;
    const int wid = threadIdx.x >> 6;
    const int lane = threadIdx.x & 63;
    const int c8 = lane << 3;
    const int r0 = (blockIdx.x * 4 + wid) * S;
    const float* pin = in + (size_t)plane * PLANE_ELEMS;
    const float rel_thr = 0.05f * __uint_as_float(vmax_bits[plane]);
    const size_t planeBase = (size_t)plane * PLANE_ELEMS;

    Row8 hist[6], raw[3], fresh[4];
    #pragma unroll
    for (int j = 0; j < 6; ++j) {
        Row8 rr = loadRow(pin, r0 - 3 + j, lane);
        hist[j] = hmax7(rr, lane);
        if (j >= 3) raw[j - 3] = rr;
    }
    #pragma unroll
    for (int j = 0; j < 4; ++j) fresh[j] = loadRow(pin, r0 + 3 + j, lane);

    #pragma unroll
    for (int k = 0; k < S / 4; ++k) {
        const int R = r0 + 4 * k;
        Row8 nxt[4];
        if (k < S / 4 - 1) {
            #pragma unroll
            for (int j = 0; j < 4; ++j) nxt[j] = loadRow(pin, R + 7 + j, lane);
        }
        Row8 hm[4];
        #pragma unroll
        for (int j = 0; j < 4; ++j) hm[j] = hmax7(fresh[j], lane);
        Row8 sfx = vmax8(hist[4], hist[5]);
        Row8 A3 = vmax8(hist[3], sfx);
        Row8 A2 = vmax8(hist[2], A3);
        Row8 A1 = vmax8(hist[1], A2);
        Row8 A0 = vmax8(hist[0], A1);
        Row8 B0 = hm[0];
        Row8 B1 = vmax8(B0, hm[1]);
        Row8 B2 = vmax8(B1, hm[2]);
        Row8 B3 = vmax8(B2, hm[3]);
        const size_t off = planeBase + (size_t)R * W + c8;
        emitAbs(oabs, off,         vmax8(A0, B0), raw[0],   rel_thr);
        emitAbs(oabs, off + W,     vmax8(A1, B1), raw[1],   rel_thr);
        emitAbs(oabs, off + 2 * W, vmax8(A2, B2), raw[2],   rel_thr);
        emitAbs(oabs, off + 3 * W, vmax8(A3, B3), fresh[0], rel_thr);
        hist[0] = hist[4]; hist[1] = hist[5];
        hist[2] = hm[0]; hist[3] = hm[1]; hist[4] = hm[2]; hist[5] = hm[3];
        raw[0] = fresh[1]; raw[1] = fresh[2]; raw[2] = fresh[3];
        fresh[0] = nxt[0]; fresh[1] = nxt[1]; fresh[2] = nxt[2]; fresh[3] = nxt[3];
    }
}

// ---------------- Pass 3a: mask = (abs != 0) ? 1 : 0 ----------------
__global__ __launch_bounds__(256) void mask_kernel(const float4* __restrict__ abs4,
                                                   float4* __restrict__ m4, int n4) {
    const int stride = gridDim.x * 256;
    for (int i = blockIdx.x * 256 + threadIdx.x; i < n4; i += stride) {
        float4 a = abs4[i];
        m4[i] = make_float4(a.x != 0.0f ? 1.0f : 0.0f, a.y != 0.0f ? 1.0f : 0.0f,
                            a.z != 0.0f ? 1.0f : 0.0f, a.w != 0.0f ? 1.0f : 0.0f);
    }
}

// ---------------- Pass 3b: rel = abs * inv_vmax[plane] ----------------
__global__ __launch_bounds__(256) void rel_kernel(const float4* __restrict__ abs4,
                                                  const unsigned int* __restrict__ vmax_bits,
                                                  float4* __restrict__ r4, int n4) {
    const int stride = gridDim.x * 256;
    for (int i = blockIdx.x * 256 + threadIdx.x; i < n4; i += stride) {
        const float inv = 1.0f / __uint_as_float(vmax_bits[i >> 16]);  // 65536 float4 / plane
        float4 a = abs4[i];
        r4[i] = make_float4(a.x * inv, a.y * inv, a.z * inv, a.w * inv);
    }
}

extern "C" void kernel_launch(void* const* d_in, const int* in_sizes, int n_in,
                              void* d_out, int out_size, void* d_ws, size_t ws_size,
                              hipStream_t stream) {
    const float* in = (const float*)d_in[0];
    float* out = (float*)d_out;
    const int N = in_sizes[0];           // 33554432
    const int planes = N / PLANE_ELEMS;  // 128
    const int n4 = N / 4;                // 8388608 float4 per stream

    float* omask = out;
    float* oabs = out + (size_t)N;
    float* orel = out + 2 * (size_t)N;

    unsigned int* vmax_bits = (unsigned int*)d_ws;
    (void)hipMemsetAsync(vmax_bits, 0, planes * sizeof(unsigned int), stream);

    vmax_kernel<<<dim3(4, planes), 256, 0, stream>>>(in, vmax_bits);
    abs_kernel<<<dim3(H / (4 * S), planes), 256, 0, stream>>>(in, vmax_bits, oabs);
    mask_kernel<<<2048, 256, 0, stream>>>((const float4*)oabs, (float4*)omask, n4);
    rel_kernel<<<2048, 256, 0, stream>>>((const float4*)oabs, vmax_bits, (float4*)orel, n4);
}